// Round 10
// baseline (516.749 us; speedup 1.0000x reference)
//
#include <hip/hip_runtime.h>
#include <hip/hip_cooperative_groups.h>
#include <hip/hip_bf16.h>
#include <math.h>

namespace cg = cooperative_groups;

#define BB 32
#define TT 256
#define ZDIM 32

typedef float vf4 __attribute__((ext_vector_type(4)));
typedef short short8 __attribute__((ext_vector_type(8)));
typedef short short4v __attribute__((ext_vector_type(4)));
typedef float f32x4 __attribute__((ext_vector_type(4)));

__device__ __forceinline__ float softplus_f(float v) {
    return fmaxf(v, 0.0f) + log1pf(expf(-fabsf(v)));
}

__device__ __forceinline__ unsigned short f2bf(float f) {
    __hip_bfloat16 h = __float2bfloat16(f);
    return *reinterpret_cast<unsigned short*>(&h);
}

// W[o][ci][k] fp32 -> Wb[ks][otile][kch][lane][8] bf16 blocked fragment order:
// a wave's A fragment for (ks, otile, kch) is the contiguous 1 KB block at
// Wb + blk*512 + lane*8  (o = otile*16 + (lane&15), ci = kch*32 + (lane>>4)*8 + j).
template<int COUT, int CIN>
__device__ void wconv_frag(const float* __restrict__ W, unsigned short* __restrict__ Wb,
                           int tid, int nthreads)
{
    const int n = 3 * COUT * CIN;
    for (int idx = tid; idx < n; idx += nthreads) {
        int j     = idx & 7;
        int lane  = (idx >> 3) & 63;
        int rest  = idx >> 9;
        int kch   = rest % (CIN / 32);
        int rest2 = rest / (CIN / 32);
        int ot    = rest2 % (COUT / 16);
        int ks    = rest2 / (COUT / 16);
        int o  = ot * 16 + (lane & 15);
        int ci = kch * 32 + (lane >> 4) * 8 + j;
        Wb[idx] = f2bf(W[(o * CIN + ci) * 3 + ks]);
    }
}

// ---------------- single cooperative mega-kernel ----------------
// ROUND 10: the whole pipeline (weight convert -> fused conv1..3 -> tril) in
// ONE cooperative launch with grid.sync() between phases, testing the last
// structural hypothesis: the ~50 us unattributed residual is inter-kernel
// launch/drain overhead (R7-R9 showed the conv itself is near its traffic
// floor: fusion -8, codegen -8, 2x TLP -3). Grid = 256 blocks = 1/CU at
// 52.5 KB LDS, 1024 threads -> co-residency guaranteed. All math, loop
// orders and rounding identical to R9 -> bit-identical outputs.
// Layouts (m89): A[m=lane&15][ci=quad*8+j], B[ci=quad*8+j][n=lane&15],
// C row = quad*4+reg (o), col = lane&15 (t).
__global__ __launch_bounds__(1024, 1)
void mega_kernel(const float* __restrict__ x,
                 const float* __restrict__ W0, const float* __restrict__ b0,
                 const float* __restrict__ W1, const float* __restrict__ b1,
                 const float* __restrict__ W2, const float* __restrict__ b2,
                 float* __restrict__ mu, float* __restrict__ dd,
                 float* __restrict__ ss, float* __restrict__ st,
                 unsigned short* __restrict__ w0b,
                 unsigned short* __restrict__ w1b,
                 unsigned short* __restrict__ w2b)
{
    cg::grid_group grid = cg::this_grid();

    __shared__ __attribute__((aligned(16))) union {
        struct {
            unsigned short xsb[64][72];   // x: [t-(t0-16)][ci], 144 B rows
            unsigned short h0s[48][264];  // h0: [t-(t0-8)][o], 528 B rows
            unsigned short h1s[34][264];  // h1: [t-(t0-1)][o]
        } c;                              // 52512 B
        struct {
            float invd[4][TT];
            float tt[4][TT];
        } t;                              // 8192 B
    } sm;

    const int tid  = threadIdx.x;
    const int wv   = tid >> 6;          // 0..15
    const int lane = tid & 63;
    const int l15  = lane & 15;
    const int quad = lane >> 4;

    // ================= phase W: weight preconvert (grid-wide) =================
    {
        const int gtid = blockIdx.x * blockDim.x + tid;
        const int nth  = gridDim.x * blockDim.x;
        wconv_frag<256, 64>(W0, w0b, gtid, nth);
        wconv_frag<256, 256>(W1, w1b, gtid, nth);
        wconv_frag<96, 256>(W2, w2b, gtid, nth);
    }
    __threadfence();
    grid.sync();

    // ================= phase C: fused conv1+conv2+conv3 =================
    {
        const int b  = blockIdx.x >> 3;
        const int t0 = (blockIdx.x & 7) * 32;
        auto& xsb = sm.c.xsb;
        auto& h0s = sm.c.h0s;
        auto& h1s = sm.c.h1s;

        // stage x: 64 rows [t0-16, t0+48) x 64 ci; waves 0-7 stage 8 rows each.
        if (wv < 8) {
            const int ci = lane;
            const int t8 = t0 - 16 + wv * 8;
            unsigned short v[8];
            if (t8 >= 0 && t8 < TT) {
                const float* xp = x + (size_t)(b * 64 + ci) * TT + t8;
                f32x4 lo = *(const f32x4*)xp;
                f32x4 hi = *(const f32x4*)(xp + 4);
                #pragma unroll
                for (int j = 0; j < 4; ++j) { v[j] = f2bf(lo[j]); v[4 + j] = f2bf(hi[j]); }
            } else {
                #pragma unroll
                for (int j = 0; j < 8; ++j) v[j] = 0;
            }
            #pragma unroll
            for (int j = 0; j < 8; ++j) xsb[wv * 8 + j][ci] = v[j];
        }
        __syncthreads();

        // layer1: wave wv owns o-tile wv, 3 t-frags at t0-8+nt*16.
        {
            f32x4 a1[3];
            {
                f32x4 bv;
                #pragma unroll
                for (int r = 0; r < 4; ++r) bv[r] = b0[wv * 16 + quad * 4 + r];
                #pragma unroll
                for (int nt = 0; nt < 3; ++nt) a1[nt] = bv;
            }
            #pragma unroll
            for (int ks = 0; ks < 3; ++ks) {
                #pragma unroll
                for (int kc = 0; kc < 64; kc += 32) {
                    short8 af = *(const short8*)(w0b + (size_t)((ks * 16 + wv) * 2 + (kc >> 5)) * 512 + lane * 8);
                    #pragma unroll
                    for (int nt = 0; nt < 3; ++nt) {
                        short8 bf = *(const short8*)&xsb[nt * 16 + l15 + ks + 7][kc + quad * 8];
                        a1[nt] = __builtin_amdgcn_mfma_f32_16x16x32_bf16(af, bf, a1[nt], 0, 0, 0);
                    }
                }
            }
            #pragma unroll
            for (int nt = 0; nt < 3; ++nt) {
                int p = nt * 16 + l15;
                int t = t0 - 8 + p;
                bool ok = (t >= 0) && (t < TT);
                short4v v;
                #pragma unroll
                for (int r = 0; r < 4; ++r)
                    v[r] = ok ? (short)f2bf(fmaxf(a1[nt][r], 0.f)) : (short)0;
                *(short4v*)&h0s[p][wv * 16 + quad * 4] = v;
            }
        }
        __syncthreads();

        // layer2: o-tile wv, 3 t-frags at t0 + {-1,15,17}.
        {
            f32x4 a2[3];
            {
                f32x4 bv;
                #pragma unroll
                for (int r = 0; r < 4; ++r) bv[r] = b1[wv * 16 + quad * 4 + r];
                #pragma unroll
                for (int nt = 0; nt < 3; ++nt) a2[nt] = bv;
            }
            #pragma unroll 1
            for (int c0 = 0; c0 < 256; c0 += 64) {
                #pragma unroll
                for (int ks = 0; ks < 3; ++ks) {
                    #pragma unroll
                    for (int kc = 0; kc < 64; kc += 32) {
                        short8 af = *(const short8*)(w1b + (size_t)((ks * 16 + wv) * 8 + ((c0 + kc) >> 5)) * 512 + lane * 8);
                        #pragma unroll
                        for (int nt = 0; nt < 3; ++nt) {
                            constexpr int F2[3] = {6, 22, 24};
                            short8 bf = *(const short8*)&h0s[F2[nt] + l15 + ks][c0 + kc + quad * 8];
                            a2[nt] = __builtin_amdgcn_mfma_f32_16x16x32_bf16(af, bf, a2[nt], 0, 0, 0);
                        }
                    }
                }
            }
            #pragma unroll
            for (int nt = 0; nt < 3; ++nt) {
                constexpr int P2[3]  = {0, 16, 18};
                constexpr int TO2[3] = {-1, 15, 17};
                int p = P2[nt] + l15;
                int t = t0 + TO2[nt] + l15;
                bool ok = (t >= 0) && (t < TT);
                short4v v;
                #pragma unroll
                for (int r = 0; r < 4; ++r)
                    v[r] = ok ? (short)f2bf(fmaxf(a2[nt][r], 0.f)) : (short)0;
                *(short4v*)&h1s[p][wv * 16 + quad * 4] = v;
            }
        }
        __syncthreads();

        // layer3 (stats): 12 tiles; waves 0-11 take one each.
        if (wv < 12) {
            const int ot = wv % 6;
            const int nt = wv / 6;
            f32x4 a3;
            #pragma unroll
            for (int r = 0; r < 4; ++r) a3[r] = b2[ot * 16 + quad * 4 + r];
            #pragma unroll 1
            for (int c0 = 0; c0 < 256; c0 += 64) {
                #pragma unroll
                for (int ks = 0; ks < 3; ++ks) {
                    #pragma unroll
                    for (int kc = 0; kc < 64; kc += 32) {
                        short8 af = *(const short8*)(w2b + (size_t)((ks * 6 + ot) * 8 + ((c0 + kc) >> 5)) * 512 + lane * 8);
                        short8 bf = *(const short8*)&h1s[nt * 16 + l15 + ks][c0 + kc + quad * 8];
                        a3 = __builtin_amdgcn_mfma_f32_16x16x32_bf16(af, bf, a3, 0, 0, 0);
                    }
                }
            }
            const int t = t0 + nt * 16 + l15;
            #pragma unroll
            for (int r = 0; r < 4; ++r) {
                int o = ot * 16 + quad * 4 + r;
                float val = a3[r];
                if (o < ZDIM) {
                    mu[(b * ZDIM + o) * TT + t] = val;
                } else {
                    int oc = o - ZDIM;
                    int z  = oc >> 1;
                    float sp = softplus_f(val);
                    if ((oc & 1) == 0) dd[(b * ZDIM + z) * TT + t] = sp + 1.f;
                    else               ss[(b * ZDIM + z) * TT + t] = sp;
                }
            }
        }
    }
    __threadfence();
    grid.sync();

    // ================= phase T: banded inverse-transpose =================
    // Each block handles 4 (b,z) pairs: wave-quad g = wv>>2 -> bz, band
    // w4 = wv&3 -> r0. Math identical to the standalone tril_kernel.
    {
        const int g    = wv >> 2;
        const int bz   = blockIdx.x * 4 + g;
        const int w4   = wv & 3;
        const int tloc = (w4 << 6) | lane;

        {
            float d  = dd[bz * TT + tloc];
            float s  = ss[bz * TT + tloc];
            float iv = 1.0f / d;
            sm.t.invd[g][tloc] = iv;
            sm.t.tt[g][tloc]   = -s * iv;
        }
        __syncthreads();

        const float* invd = sm.t.invd[g];
        const float* tt   = sm.t.tt[g];
        const int r0 = w4 * 64;
        const int c0 = lane * 4;

        float p0 = 1.f, p1 = 1.f, p2 = 1.f, p3 = 1.f;
        for (int k = 0; k < r0 - 1; ++k) {
            float tm = tt[k];
            p0 = (k >= c0    ) ? p0 * tm : p0;
            p1 = (k >= c0 + 1) ? p1 * tm : p1;
            p2 = (k >= c0 + 2) ? p2 * tm : p2;
            p3 = (k >= c0 + 3) ? p3 * tm : p3;
        }
        p0 = (c0     < r0) ? p0 : 0.f;
        p1 = (c0 + 1 < r0) ? p1 : 0.f;
        p2 = (c0 + 2 < r0) ? p2 : 0.f;
        p3 = (c0 + 3 < r0) ? p3 : 0.f;

        float* orow = st + (size_t)bz * TT * TT + (size_t)r0 * TT + c0;

        #pragma unroll 2
        for (int r = r0; r < r0 + 64; ++r) {
            float tm = (r > 0) ? tt[r - 1] : 0.0f;
            p0 = (r == c0    ) ? 1.0f : p0 * tm;
            p1 = (r == c0 + 1) ? 1.0f : p1 * tm;
            p2 = (r == c0 + 2) ? 1.0f : p2 * tm;
            p3 = (r == c0 + 3) ? 1.0f : p3 * tm;
            float id = invd[r];
            vf4 v;
            v.x = p0 * id; v.y = p1 * id; v.z = p2 * id; v.w = p3 * id;
            v.x = isfinite(v.x) ? v.x : 0.0f;
            v.y = isfinite(v.y) ? v.y : 0.0f;
            v.z = isfinite(v.z) ? v.z : 0.0f;
            v.w = isfinite(v.w) ? v.w : 0.0f;
            __builtin_nontemporal_store(v, (vf4*)orow);
            orow += TT;
        }
    }
}

extern "C" void kernel_launch(void* const* d_in, const int* in_sizes, int n_in,
                              void* d_out, int out_size, void* d_ws, size_t ws_size,
                              hipStream_t stream)
{
    const float* x  = (const float*)d_in[0];
    const float* W0 = (const float*)d_in[1];
    const float* b0 = (const float*)d_in[2];
    const float* W1 = (const float*)d_in[3];
    const float* b1 = (const float*)d_in[4];
    const float* W2 = (const float*)d_in[5];
    const float* b2 = (const float*)d_in[6];

    float* out = (float*)d_out;
    float* mu  = out;                          // (32,32,256)
    float* st  = out + BB * ZDIM * TT;         // (32,32,256,256)

    // workspace: fp32 dd/ss + bf16 blocked-fragment weights
    float* dd = (float*)d_ws;                              // 262,144 floats
    float* ss = dd + BB * ZDIM * TT;                       // 262,144 floats
    unsigned short* w0b = (unsigned short*)(ss + BB * ZDIM * TT);  // 3*256*64
    unsigned short* w1b = w0b + 3 * 256 * 64;                      // 3*256*256
    unsigned short* w2b = w1b + 3 * 256 * 256;                     // 3*96*256

    void* args[] = {
        (void*)&x, (void*)&W0, (void*)&b0, (void*)&W1, (void*)&b1,
        (void*)&W2, (void*)&b2, (void*)&mu, (void*)&dd, (void*)&ss,
        (void*)&st, (void*)&w0b, (void*)&w1b, (void*)&w2b
    };
    // one cooperative launch: 256 blocks (1/CU, co-resident), 1024 threads
    hipLaunchCooperativeKernel((void*)mega_kernel, dim3(BB * 8), dim3(1024),
                               args, 0, stream);
}

// Round 11
// 294.300 us; speedup vs baseline: 1.7559x; 1.7559x over previous
//
#include <hip/hip_runtime.h>
#include <hip/hip_bf16.h>
#include <math.h>

#define BB 32
#define TT 256
#define ZDIM 32

typedef float vf4 __attribute__((ext_vector_type(4)));
typedef short short8 __attribute__((ext_vector_type(8)));
typedef short short4v __attribute__((ext_vector_type(4)));
typedef float f32x4 __attribute__((ext_vector_type(4)));

__device__ __forceinline__ float softplus_f(float v) {
    return fmaxf(v, 0.0f) + log1pf(expf(-fabsf(v)));
}

__device__ __forceinline__ unsigned short f2bf(float f) {
    __hip_bfloat16 h = __float2bfloat16(f);
    return *reinterpret_cast<unsigned short*>(&h);
}

// ---------------- weight preconvert: blocked fragment layout ----------------
// W[o][ci][k] fp32 -> Wb[ks][otile][kch][lane][8] bf16: a wave's A fragment
// for (ks, otile, 32-ci chunk kch) is the contiguous 1 KB block
// Wb + blk*512 + lane*8  (o = otile*16 + (lane&15), ci = kch*32 + (lane>>4)*8 + j).
template<int COUT, int CIN>
__device__ void wconv_frag(const float* __restrict__ W, unsigned short* __restrict__ Wb,
                           int tid, int nthreads)
{
    const int n = 3 * COUT * CIN;
    for (int idx = tid; idx < n; idx += nthreads) {
        int j     = idx & 7;
        int lane  = (idx >> 3) & 63;
        int rest  = idx >> 9;                 // (ks*(COUT/16)+ot)*(CIN/32)+kch
        int kch   = rest % (CIN / 32);
        int rest2 = rest / (CIN / 32);
        int ot    = rest2 % (COUT / 16);
        int ks    = rest2 / (COUT / 16);
        int o  = ot * 16 + (lane & 15);
        int ci = kch * 32 + (lane >> 4) * 8 + j;
        Wb[idx] = f2bf(W[(o * CIN + ci) * 3 + ks]);
    }
}

__global__ __launch_bounds__(256)
void wconv_kernel(const float* __restrict__ W0, const float* __restrict__ W1,
                  const float* __restrict__ W2, unsigned short* __restrict__ w0b,
                  unsigned short* __restrict__ w1b, unsigned short* __restrict__ w2b)
{
    const int tid = blockIdx.x * blockDim.x + threadIdx.x;
    const int nth = gridDim.x * blockDim.x;
    wconv_frag<256, 64>(W0, w0b, tid, nth);
    wconv_frag<256, 256>(W1, w1b, tid, nth);
    wconv_frag<96, 256>(W2, w2b, tid, nth);
}

// ---------------- fused conv1+conv2+conv3, 16-wave (R9, unchanged) ----------------
// Layouts (m89): A[m=lane&15][ci=quad*8+j], B[ci=quad*8+j][n=lane&15],
// C row = quad*4+reg (o), col = lane&15 (t).
__global__ __launch_bounds__(1024, 1)
void fused_conv(const float* __restrict__ x,
                const unsigned short* __restrict__ w0b,
                const unsigned short* __restrict__ w1b,
                const unsigned short* __restrict__ w2b,
                const float* __restrict__ b0, const float* __restrict__ b1,
                const float* __restrict__ b2,
                float* __restrict__ mu, float* __restrict__ dd,
                float* __restrict__ ss)
{
    constexpr int XPAD = 72;    // 144 B rows (aligned b128 reads)
    constexpr int HPAD = 264;   // 528 B rows (aligned; 4-dw bank shift per row)

    __shared__ __attribute__((aligned(16))) unsigned short xsb[64][XPAD]; // x: [t-(t0-16)][ci]
    __shared__ __attribute__((aligned(16))) unsigned short h0s[48][HPAD]; // h0: [t-(t0-8)][o]
    __shared__ __attribute__((aligned(16))) unsigned short h1s[34][HPAD]; // h1: [t-(t0-1)][o]

    const int b    = blockIdx.x;
    const int t0   = blockIdx.y * 32;
    const int tid  = threadIdx.x;
    const int wv   = tid >> 6;          // 0..15
    const int lane = tid & 63;
    const int l15  = lane & 15;
    const int quad = lane >> 4;

    // ---- stage x: 64 rows [t0-16, t0+48) x 64 ci; waves 0-7 stage 8 rows each.
    if (wv < 8) {
        const int ci = lane;
        const int t8 = t0 - 16 + wv * 8;
        unsigned short v[8];
        if (t8 >= 0 && t8 < TT) {
            const float* xp = x + (size_t)(b * 64 + ci) * TT + t8;
            f32x4 lo = *(const f32x4*)xp;
            f32x4 hi = *(const f32x4*)(xp + 4);
            #pragma unroll
            for (int j = 0; j < 4; ++j) { v[j] = f2bf(lo[j]); v[4 + j] = f2bf(hi[j]); }
        } else {
            #pragma unroll
            for (int j = 0; j < 8; ++j) v[j] = 0;
        }
        #pragma unroll
        for (int j = 0; j < 8; ++j) xsb[wv * 8 + j][ci] = v[j];
    }
    __syncthreads();

    // ---- layer1: wave wv owns o-tile wv, 3 t-frags at t0-8+nt*16.
    {
        f32x4 a1[3];
        {
            f32x4 bv;
            #pragma unroll
            for (int r = 0; r < 4; ++r) bv[r] = b0[wv * 16 + quad * 4 + r];
            #pragma unroll
            for (int nt = 0; nt < 3; ++nt) a1[nt] = bv;
        }
        #pragma unroll
        for (int ks = 0; ks < 3; ++ks) {
            #pragma unroll
            for (int kc = 0; kc < 64; kc += 32) {
                short8 af = *(const short8*)(w0b + (size_t)((ks * 16 + wv) * 2 + (kc >> 5)) * 512 + lane * 8);
                #pragma unroll
                for (int nt = 0; nt < 3; ++nt) {
                    short8 bf = *(const short8*)&xsb[nt * 16 + l15 + ks + 7][kc + quad * 8];
                    a1[nt] = __builtin_amdgcn_mfma_f32_16x16x32_bf16(af, bf, a1[nt], 0, 0, 0);
                }
            }
        }
        #pragma unroll
        for (int nt = 0; nt < 3; ++nt) {
            int p = nt * 16 + l15;
            int t = t0 - 8 + p;
            bool ok = (t >= 0) && (t < TT);
            short4v v;
            #pragma unroll
            for (int r = 0; r < 4; ++r)
                v[r] = ok ? (short)f2bf(fmaxf(a1[nt][r], 0.f)) : (short)0;
            *(short4v*)&h0s[p][wv * 16 + quad * 4] = v;
        }
    }
    __syncthreads();

    // ---- layer2: o-tile wv, 3 t-frags at t0 + {-1,15,17}.
    {
        f32x4 a2[3];
        {
            f32x4 bv;
            #pragma unroll
            for (int r = 0; r < 4; ++r) bv[r] = b1[wv * 16 + quad * 4 + r];
            #pragma unroll
            for (int nt = 0; nt < 3; ++nt) a2[nt] = bv;
        }
        #pragma unroll 1
        for (int c0 = 0; c0 < 256; c0 += 64) {
            #pragma unroll
            for (int ks = 0; ks < 3; ++ks) {
                #pragma unroll
                for (int kc = 0; kc < 64; kc += 32) {
                    short8 af = *(const short8*)(w1b + (size_t)((ks * 16 + wv) * 8 + ((c0 + kc) >> 5)) * 512 + lane * 8);
                    #pragma unroll
                    for (int nt = 0; nt < 3; ++nt) {
                        constexpr int F2[3] = {6, 22, 24};
                        short8 bf = *(const short8*)&h0s[F2[nt] + l15 + ks][c0 + kc + quad * 8];
                        a2[nt] = __builtin_amdgcn_mfma_f32_16x16x32_bf16(af, bf, a2[nt], 0, 0, 0);
                    }
                }
            }
        }
        #pragma unroll
        for (int nt = 0; nt < 3; ++nt) {
            constexpr int P2[3]  = {0, 16, 18};
            constexpr int TO2[3] = {-1, 15, 17};
            int p = P2[nt] + l15;
            int t = t0 + TO2[nt] + l15;
            bool ok = (t >= 0) && (t < TT);
            short4v v;
            #pragma unroll
            for (int r = 0; r < 4; ++r)
                v[r] = ok ? (short)f2bf(fmaxf(a2[nt][r], 0.f)) : (short)0;
            *(short4v*)&h1s[p][wv * 16 + quad * 4] = v;
        }
    }
    __syncthreads();

    // ---- layer3 (stats): 12 tiles; waves 0-11 take one each.
    if (wv < 12) {
        const int ot = wv % 6;
        const int nt = wv / 6;
        f32x4 a3;
        #pragma unroll
        for (int r = 0; r < 4; ++r) a3[r] = b2[ot * 16 + quad * 4 + r];
        #pragma unroll 1
        for (int c0 = 0; c0 < 256; c0 += 64) {
            #pragma unroll
            for (int ks = 0; ks < 3; ++ks) {
                #pragma unroll
                for (int kc = 0; kc < 64; kc += 32) {
                    short8 af = *(const short8*)(w2b + (size_t)((ks * 6 + ot) * 8 + ((c0 + kc) >> 5)) * 512 + lane * 8);
                    short8 bf = *(const short8*)&h1s[nt * 16 + l15 + ks][c0 + kc + quad * 8];
                    a3 = __builtin_amdgcn_mfma_f32_16x16x32_bf16(af, bf, a3, 0, 0, 0);
                }
            }
        }
        const int t = t0 + nt * 16 + l15;
        #pragma unroll
        for (int r = 0; r < 4; ++r) {
            int o = ot * 16 + quad * 4 + r;
            float val = a3[r];
            if (o < ZDIM) {
                mu[(b * ZDIM + o) * TT + t] = val;
            } else {
                int oc = o - ZDIM;
                int z  = oc >> 1;
                float sp = softplus_f(val);
                if ((oc & 1) == 0) dd[(b * ZDIM + z) * TT + t] = sp + 1.f;
                else               ss[(b * ZDIM + z) * TT + t] = sp;
            }
        }
    }
}

// ---------------- banded inverse-transpose ----------------
// ROUND 11: ONE change vs R9 — plain vector stores instead of
// __builtin_nontemporal_store. R10's mega counters exposed the session-long
// bottleneck: the nt (L2-bypass) write path drains at ~1 TB/s (13% of peak);
// the fill and m13 µbench hit 6.3-6.4 TB/s with normal (L2-mediated) stores.
// Store values identical -> bit-identical output.
__global__ __launch_bounds__(256)
void tril_kernel(const float* __restrict__ dd, const float* __restrict__ ss,
                 float* __restrict__ out)
{
    __shared__ float invd[TT];
    __shared__ float tt[TT];

    const int bz  = blockIdx.x;
    const int tid = threadIdx.x;

    {
        float d  = dd[bz * TT + tid];
        float s  = ss[bz * TT + tid];
        float iv = 1.0f / d;
        invd[tid] = iv;
        tt[tid]   = -s * iv;
    }
    __syncthreads();

    const int r0 = (tid >> 6) * 64;
    const int c0 = (tid & 63) * 4;

    float p0 = 1.f, p1 = 1.f, p2 = 1.f, p3 = 1.f;
    for (int k = 0; k < r0 - 1; ++k) {
        float tm = tt[k];
        p0 = (k >= c0    ) ? p0 * tm : p0;
        p1 = (k >= c0 + 1) ? p1 * tm : p1;
        p2 = (k >= c0 + 2) ? p2 * tm : p2;
        p3 = (k >= c0 + 3) ? p3 * tm : p3;
    }
    p0 = (c0     < r0) ? p0 : 0.f;
    p1 = (c0 + 1 < r0) ? p1 : 0.f;
    p2 = (c0 + 2 < r0) ? p2 : 0.f;
    p3 = (c0 + 3 < r0) ? p3 : 0.f;

    float* orow = out + (size_t)bz * TT * TT + (size_t)r0 * TT + c0;

    #pragma unroll 2
    for (int r = r0; r < r0 + 64; ++r) {
        float tm = (r > 0) ? tt[r - 1] : 0.0f;
        p0 = (r == c0    ) ? 1.0f : p0 * tm;
        p1 = (r == c0 + 1) ? 1.0f : p1 * tm;
        p2 = (r == c0 + 2) ? 1.0f : p2 * tm;
        p3 = (r == c0 + 3) ? 1.0f : p3 * tm;
        float id = invd[r];
        vf4 v;
        v.x = p0 * id; v.y = p1 * id; v.z = p2 * id; v.w = p3 * id;
        v.x = isfinite(v.x) ? v.x : 0.0f;
        v.y = isfinite(v.y) ? v.y : 0.0f;
        v.z = isfinite(v.z) ? v.z : 0.0f;
        v.w = isfinite(v.w) ? v.w : 0.0f;
        *(vf4*)orow = v;            // plain store: L2-mediated write path
        orow += TT;
    }
}

extern "C" void kernel_launch(void* const* d_in, const int* in_sizes, int n_in,
                              void* d_out, int out_size, void* d_ws, size_t ws_size,
                              hipStream_t stream)
{
    const float* x  = (const float*)d_in[0];
    const float* W0 = (const float*)d_in[1];
    const float* b0 = (const float*)d_in[2];
    const float* W1 = (const float*)d_in[3];
    const float* b1 = (const float*)d_in[4];
    const float* W2 = (const float*)d_in[5];
    const float* b2 = (const float*)d_in[6];

    float* out = (float*)d_out;
    float* mu  = out;                          // (32,32,256)
    float* st  = out + BB * ZDIM * TT;         // (32,32,256,256)

    // workspace: fp32 dd/ss + bf16 blocked-fragment weights (no intermediates)
    float* dd = (float*)d_ws;                              // 262,144 floats
    float* ss = dd + BB * ZDIM * TT;                       // 262,144 floats
    unsigned short* w0b = (unsigned short*)(ss + BB * ZDIM * TT);  // 3*256*64
    unsigned short* w1b = w0b + 3 * 256 * 64;                      // 3*256*256
    unsigned short* w2b = w1b + 3 * 256 * 256;                     // 3*96*256

    // weight preconvert to blocked fragment order
    wconv_kernel<<<dim3(256), 256, 0, stream>>>(W0, W1, W2, w0b, w1b, w2b);
    // fused conv1+conv2+conv3: 256 blocks (1/CU), 16 waves, 3 barriers
    fused_conv<<<dim3(BB, 8), 1024, 0, stream>>>(
        x, w0b, w1b, w2b, b0, b1, b2, mu, dd, ss);
    // banded inverse-transpose, write-bound; 1 block = 4 bands per (b,z)
    tril_kernel<<<dim3(BB * ZDIM), 256, 0, stream>>>(dd, ss, st);
}